// Round 7
// baseline (721570.703 us; speedup 1.0000x reference)
//
#include <hip/hip_runtime.h>
#include <hip/hip_bf16.h>

#define VV 50257
#define DD 256
#define HH 512
#define BB 64
#define SS 512
#define H3 1536
#define NWG 16          // scan workgroups (elected onto ONE XCD)
#define NLAUNCH 128     // launched WGs for the election
#define JSL 32          // hidden units per scan WG
#define UCPAD 97        // 96 cols (interleaved [z r h]x16 per ng) + 1 pad
#define UBYTES (64*UCPAD*16)   // 99328 B per-WG padded U slice image
#define HOUTB 4096             // publish staging tile in LDS [64][32] f16
#define HBYTES (BB*HH*2)       // 65536 B f16 h image, row-major [64][512]

typedef _Float16 f16x8 __attribute__((ext_vector_type(8)));
typedef _Float16 f16x4 __attribute__((ext_vector_type(4)));
typedef float f32x4 __attribute__((ext_vector_type(4)));
typedef unsigned int u32x4 __attribute__((ext_vector_type(4)));

#define AS1 __attribute__((address_space(1)))
#define AS3 __attribute__((address_space(3)))
#define GLL16(g, s) __builtin_amdgcn_global_load_lds((const AS1 char*)(g), (AS3 char*)(s), 16, 0, 0)

// ---------------------------------------------------------------------------
// Pack W (f32 [256][1536]) -> f16 k-major
// ---------------------------------------------------------------------------
__global__ __launch_bounds__(256) void kPackW(const float* __restrict__ W,
                                              _Float16* __restrict__ wsW) {
    int idx = blockIdx.x * 256 + threadIdx.x;     // 32 kb * 1536 col
    int kb = idx / H3, col = idx % H3;
    f16x8 v;
    #pragma unroll
    for (int e = 0; e < 8; ++e) v[e] = (_Float16)W[(size_t)(kb*8+e)*H3 + col];
    *(f16x8*)(wsW + (size_t)idx*8) = v;
}

// ---------------------------------------------------------------------------
// Pack U -> per-rank padded k-major images, gate-interleaved per 16-col block
// ---------------------------------------------------------------------------
__global__ __launch_bounds__(256) void kPackU(const float* __restrict__ U,
                                              _Float16* __restrict__ wsU) {
    int wgp = blockIdx.x;                          // 16 ranks
    for (int idx = threadIdx.x; idx < 64*UCPAD; idx += 256) {
        int kb = idx / UCPAD, c = idx % UCPAD;
        int cc = (c == 96) ? 0 : c;
        int ng = cc / 48, rem = cc % 48;
        int g = rem / 16, jl = ng*16 + (rem % 16);
        int gcol = g*HH + wgp*JSL + jl;
        f16x8 v;
        #pragma unroll
        for (int e = 0; e < 8; ++e) v[e] = (_Float16)U[(size_t)(kb*8+e)*H3 + gcol];
        *(f16x8*)(wsU + (size_t)wgp*(UBYTES/2) + (size_t)idx*8) = v;
    }
}

// maskbits[t] bit r = (tokens[r][t] != 0); zero scan flags + election slots
__global__ __launch_bounds__(256) void kMask(const int* __restrict__ tokens,
                                             unsigned long long* __restrict__ mb,
                                             unsigned int* __restrict__ sync) {
    int t = blockIdx.x * 256 + threadIdx.x;
    if (t < SS) {
        unsigned long long m = 0ull;
        for (int r = 0; r < BB; ++r)
            m |= (unsigned long long)(tokens[r*SS + t] != 0) << r;
        mb[t] = m;
    }
    if (blockIdx.x == 0 && threadIdx.x < NWG)
        __hip_atomic_store(sync + threadIdx.x * 16, 0u,
                           __ATOMIC_RELAXED, __HIP_MEMORY_SCOPE_AGENT);
    if (blockIdx.x == 0 && threadIdx.x < 32)
        __hip_atomic_store(sync + 512 + threadIdx.x, 0u,
                           __ATOMIC_RELAXED, __HIP_MEMORY_SCOPE_AGENT);
}

// ---------------------------------------------------------------------------
// K1: xp[t][col][b] (f16) = (emb[tokens] @ W + b0)
// ---------------------------------------------------------------------------
__global__ __launch_bounds__(256) void k1_embed_proj(
    const int* __restrict__ tokens, const float* __restrict__ emb,
    const _Float16* __restrict__ wsW, const float* __restrict__ bias,
    _Float16* __restrict__ xp)
{
    const int s  = blockIdx.y;
    const int nt = blockIdx.x;
    const int tid = threadIdx.x;
    __shared__ _Float16 aLds[64 * 256];

    for (int c = tid; c < 64 * 32; c += 256) {
        int row = c >> 5, kc = c & 31;
        int tok = tokens[row * SS + s];
        const float* src = emb + (size_t)tok * DD + kc * 8;
        float4 f0 = *(const float4*)(src);
        float4 f1 = *(const float4*)(src + 4);
        f16x8 v;
        v[0]=(_Float16)f0.x; v[1]=(_Float16)f0.y; v[2]=(_Float16)f0.z; v[3]=(_Float16)f0.w;
        v[4]=(_Float16)f1.x; v[5]=(_Float16)f1.y; v[6]=(_Float16)f1.z; v[7]=(_Float16)f1.w;
        int byte = row * 512 + ((kc * 16) ^ ((row & 7) << 4));
        *(f16x8*)((char*)aLds + byte) = v;
    }
    __syncthreads();

    const int w = tid >> 6, l = tid & 63;
    const int l15 = l & 15, lk = l >> 4;
    const int colbase = nt * 128;
    f32x4 acc[8] = {};

    for (int ks = 0; ks < 8; ++ks) {
        int arow = 16 * w + l15;
        f16x8 aF = *(const f16x8*)((const char*)aLds + arow*512 + (((ks*32 + lk*8)*2) ^ ((arow & 7) << 4)));
        int kb = ks*4 + lk;
        #pragma unroll
        for (int ns = 0; ns < 8; ++ns) {
            int col = colbase + ns * 16 + l15;
            f16x8 bF = *(const f16x8*)(wsW + ((size_t)kb * H3 + col) * 8);
            acc[ns] = __builtin_amdgcn_mfma_f32_16x16x32_f16(aF, bF, acc[ns], 0, 0, 0);
        }
    }
    #pragma unroll
    for (int ns = 0; ns < 8; ++ns) {
        int col = colbase + ns * 16 + l15;
        float b0 = bias[col];
        f16x4 vv;
        #pragma unroll
        for (int i = 0; i < 4; ++i) vv[i] = (_Float16)(acc[ns][i] + b0);
        *(f16x4*)(xp + ((size_t)s * H3 + col) * BB + 16*w + lk*4) = vv;
    }
}

// ---------------------------------------------------------------------------
// K2: persistent GRU scan — same-XCD, local-L2 rendezvous.
// 128 WGs launched; 16 elected onto one XCD (shared, coherent L2).
// Producers: plain write-through stores (land in local L2) + vmcnt + barrier
// + plain flag store.  Consumers: poll = buffer_inv sc0 (L1 invalidate) +
// plain load; after barrier one buffer_inv sc0, then plain dwordx4 h loads
// (local L2 hits).  All spins bounded.  t=0 skips h (h0=0).
// sync[]: [r*16] step flags (r<16); [512+x] per-XCD claims; [528] winner.
// ---------------------------------------------------------------------------
__global__ __launch_bounds__(256) void k2_scan(
    const _Float16* __restrict__ xp, const _Float16* __restrict__ wsU,
    const float* __restrict__ bias, const unsigned long long* __restrict__ maskbits,
    char* __restrict__ hpub, float* __restrict__ hlast,
    unsigned int* __restrict__ sync)
{
    extern __shared__ char lds[];
    char* uLds = lds;               // UBYTES
    char* hOut = lds + UBYTES;      // HOUTB: [64 rows][32 cols] f16
    const int tid = threadIdx.x;

    // ---- XCD election ----
    __shared__ int sRank, sWin, sXcd;
    if (tid == 0) {
        int xcd;
        asm volatile("s_getreg_b32 %0, hwreg(20, 0, 32)" : "=s"(xcd));  // HW_REG_XCC_ID
        xcd &= 7;
        unsigned slot = __hip_atomic_fetch_add(&sync[512 + xcd], 1u,
                          __ATOMIC_RELAXED, __HIP_MEMORY_SCOPE_AGENT);
        if (slot == NWG - 1) {
            unsigned exp0 = 0;
            __hip_atomic_compare_exchange_strong(&sync[528], &exp0, (unsigned)(xcd + 1),
                __ATOMIC_RELAXED, __ATOMIC_RELAXED, __HIP_MEMORY_SCOPE_AGENT);
        }
        unsigned wv; long n = 0;
        do {
            wv = __hip_atomic_load(&sync[528], __ATOMIC_RELAXED, __HIP_MEMORY_SCOPE_AGENT);
        } while (wv == 0 && ++n < 2000000L);
        sWin = (int)wv - 1;
        sXcd = xcd;
        sRank = (int)slot;
    }
    __syncthreads();
    if (sXcd != sWin || sRank >= NWG) return;   // not a participant
    const int rank = sRank;

    const int w = tid >> 6, l = tid & 63;
    const int l15 = l & 15, lk = l >> 4;
    const int mg = w >> 1, ng = w & 1;          // 2x2 wave split
    const int jg = rank * JSL;
    const int j  = jg + ng*16 + l15;            // this thread's hidden col

    // stage resident padded U slice (linear image -> linear LDS)
    {
        const char* src = (const char*)wsU + (size_t)rank * UBYTES;
        for (int base = 0; base < UBYTES; base += 4096) {
            int off = base + tid * 16;
            if (off < UBYTES) GLL16(src + off, uLds + off);
        }
    }
    const float b1z = bias[H3 + j];
    const float b1r = bias[H3 + HH + j];
    const float b1h = bias[H3 + 2*HH + j];
    float hold[2][4] = {};                      // [msub][i]
    __syncthreads();

    for (int t = 0; t < SS; ++t) {
        // gate-phase xp loads (read-only, issue before the wait)
        const _Float16* xpt = xp + (size_t)t * H3 * BB;
        const int b0 = mg*32 + lk*4;
        f16x4 xz0 = *(const f16x4*)(xpt + (0*HH + j)*BB + b0);
        f16x4 xz1 = *(const f16x4*)(xpt + (0*HH + j)*BB + b0 + 16);
        f16x4 xr0 = *(const f16x4*)(xpt + (1*HH + j)*BB + b0);
        f16x4 xr1 = *(const f16x4*)(xpt + (1*HH + j)*BB + b0 + 16);
        f16x4 xh0 = *(const f16x4*)(xpt + (2*HH + j)*BB + b0);
        f16x4 xh1 = *(const f16x4*)(xpt + (2*HH + j)*BB + b0 + 16);
        unsigned long long mb = maskbits[t];

        f32x4 az0 = {}, az1 = {}, ar0 = {}, ar1 = {}, ah0 = {}, ah1 = {};

        if (t > 0) {
            // wait for h(t): L1-invalidate + plain load (local L2 hit)
            if (tid < NWG) {
                unsigned long long fa = (unsigned long long)(sync + tid * 16);
                unsigned v; int n = 0;
                do {
                    asm volatile("buffer_inv sc0\n\t"
                                 "global_load_dword %0, %1, off\n\t"
                                 "s_waitcnt vmcnt(0)"
                                 : "=v"(v) : "v"(fa) : "memory");
                } while (v < (unsigned)t && ++n < 20000);
            }
            __syncthreads();
            asm volatile("buffer_inv sc0" ::: "memory");

            // A-fragments: 32 x plain dwordx4 from local L2
            const char* hsrc = hpub + (size_t)(t & 1) * HBYTES;
            unsigned long long hb0 = (unsigned long long)(hsrc + (mg*32 + l15)*1024 + lk*16);
            unsigned long long hb1 = hb0 + 16*1024;
            u32x4 hf0[16], hf1[16];
#define LDH(arr, base, i, off) asm volatile("global_load_dwordx4 %0, %1, off offset:" off \
                                 : "=v"(arr[i]) : "v"(base) : "memory")
            LDH(hf0,hb0,0,"0");    LDH(hf0,hb0,1,"64");   LDH(hf0,hb0,2,"128");  LDH(hf0,hb0,3,"192");
            LDH(hf0,hb0,4,"256");  LDH(hf0,hb0,5,"320");  LDH(hf0,hb0,6,"384");  LDH(hf0,hb0,7,"448");
            LDH(hf0,hb0,8,"512");  LDH(hf0,hb0,9,"576");  LDH(hf0,hb0,10,"640"); LDH(hf0,hb0,11,"704");
            LDH(hf0,hb0,12,"768"); LDH(hf0,hb0,13,"832"); LDH(hf0,hb0,14,"896"); LDH(hf0,hb0,15,"960");
            LDH(hf1,hb1,0,"0");    LDH(hf1,hb1,1,"64");   LDH(hf1,hb1,2,"128");  LDH(hf1,hb1,3,"192");
            LDH(hf1,hb1,4,"256");  LDH(hf1,hb1,5,"320");  LDH(hf1,hb1,6,"384");  LDH(hf1,hb1,7,"448");
            LDH(hf1,hb1,8,"512");  LDH(hf1,hb1,9,"576");  LDH(hf1,hb1,10,"640"); LDH(hf1,hb1,11,"704");
            LDH(hf1,hb1,12,"768"); LDH(hf1,hb1,13,"832"); LDH(hf1,hb1,14,"896"); LDH(hf1,hb1,15,"960");
#undef LDH
            asm volatile("s_waitcnt vmcnt(0)" ::: "memory");
            __builtin_amdgcn_sched_barrier(0);

            // rec = h @ Uslice : 2 m-subtiles x 3 gates (this wave's 16 cols)
            #pragma unroll
            for (int ks = 0; ks < 16; ++ks) {
                f16x8 a0 = __builtin_bit_cast(f16x8, hf0[ks]);
                f16x8 a1 = __builtin_bit_cast(f16x8, hf1[ks]);
                const char* ub = uLds + (size_t)(ks*4 + lk) * (UCPAD*16) + ng*768 + l15*16;
                f16x8 bz = *(const f16x8*)(ub);
                f16x8 br = *(const f16x8*)(ub + 256);
                f16x8 bh = *(const f16x8*)(ub + 512);
                az0 = __builtin_amdgcn_mfma_f32_16x16x32_f16(a0, bz, az0, 0, 0, 0);
                az1 = __builtin_amdgcn_mfma_f32_16x16x32_f16(a1, bz, az1, 0, 0, 0);
                ar0 = __builtin_amdgcn_mfma_f32_16x16x32_f16(a0, br, ar0, 0, 0, 0);
                ar1 = __builtin_amdgcn_mfma_f32_16x16x32_f16(a1, br, ar1, 0, 0, 0);
                ah0 = __builtin_amdgcn_mfma_f32_16x16x32_f16(a0, bh, ah0, 0, 0, 0);
                ah1 = __builtin_amdgcn_mfma_f32_16x16x32_f16(a1, bh, ah1, 0, 0, 0);
            }
        }

        // gates
        _Float16 hv[2][4];
        #pragma unroll
        for (int ms = 0; ms < 2; ++ms) {
            f32x4 az = ms ? az1 : az0;
            f32x4 ar = ms ? ar1 : ar0;
            f32x4 ah = ms ? ah1 : ah0;
            f16x4 xz = ms ? xz1 : xz0;
            f16x4 xr = ms ? xr1 : xr0;
            f16x4 xh = ms ? xh1 : xh0;
            #pragma unroll
            for (int i = 0; i < 4; ++i) {
                int row = mg*32 + ms*16 + lk*4 + i;
                float z  = 1.f / (1.f + __expf(-((float)xz[i] + az[i] + b1z)));
                float rg = 1.f / (1.f + __expf(-((float)xr[i] + ar[i] + b1r)));
                float ag = (float)xh[i] + rg * (ah[i] + b1h);
                float hc = 1.f - 2.f / (__expf(2.f * ag) + 1.f);
                float hn = z * hold[ms][i] + (1.f - z) * hc;
                if (!((mb >> row) & 1ull)) hn = hold[ms][i];
                hold[ms][i] = hn;
                hv[ms][i] = (_Float16)hn;
            }
        }

        if (t < SS - 1) {
            // LDS-transpose publish tile: hOut[64 rows][32 cols] f16
            #pragma unroll
            for (int ms = 0; ms < 2; ++ms)
                #pragma unroll
                for (int i = 0; i < 4; ++i)
                    *(_Float16*)(hOut + (mg*32 + ms*16 + lk*4 + i)*64 + (ng*16 + l15)*2) = hv[ms][i];
            __syncthreads();
            // coalesced publish: plain write-through -> local L2
            char* hnxt = hpub + (size_t)((t+1) & 1) * HBYTES;
            u32x4 blkv = *(const u32x4*)(hOut + tid*16);
            unsigned long long pa = (unsigned long long)
                (hnxt + (tid >> 2)*1024 + jg*2 + (tid & 3)*16);
            asm volatile("global_store_dwordx4 %0, %1, off"
                         :: "v"(pa), "v"(blkv) : "memory");
            asm volatile("s_waitcnt vmcnt(0)" ::: "memory");
            __syncthreads();
            if (tid == 0) {
                unsigned fv = (unsigned)(t + 1);
                unsigned long long fa = (unsigned long long)(sync + rank * 16);
                asm volatile("global_store_dword %0, %1, off"
                             :: "v"(fa), "v"(fv) : "memory");
            }
        } else {
            #pragma unroll
            for (int ms = 0; ms < 2; ++ms)
                #pragma unroll
                for (int i = 0; i < 4; ++i) {
                    int row = mg*32 + ms*16 + lk*4 + i;
                    hlast[row*HH + j] = hold[ms][i];
                }
        }
    }
}

// ---------------------------------------------------------------------------
// K3a: logits + per-WG softmax partials
// ---------------------------------------------------------------------------
__global__ __launch_bounds__(256) void k3_logits(
    const float* __restrict__ hin, const float* __restrict__ Wd,
    const float* __restrict__ bd, float* __restrict__ out,
    float* __restrict__ partials)
{
    const int nt = blockIdx.x;
    const int tid = threadIdx.x;
    __shared__ _Float16 hLds[64 * 512];

    for (int c = tid; c < 64 * 64; c += 256) {
        int row = c >> 6, kc = c & 63;
        const float* src = hin + row * HH + kc * 8;
        float4 f0 = *(const float4*)(src);
        float4 f1 = *(const float4*)(src + 4);
        f16x8 v;
        v[0]=(_Float16)f0.x; v[1]=(_Float16)f0.y; v[2]=(_Float16)f0.z; v[3]=(_Float16)f0.w;
        v[4]=(_Float16)f1.x; v[5]=(_Float16)f1.y; v[6]=(_Float16)f1.z; v[7]=(_Float16)f1.w;
        int byte = row * 1024 + ((kc * 16) ^ ((row & 7) << 4));
        *(f16x8*)((char*)hLds + byte) = v;
    }
    __syncthreads();

    const int w = tid >> 6, l = tid & 63;
    const int l15 = l & 15, lk = l >> 4;
    f32x4 acc[8] = {};

    for (int ks = 0; ks < 16; ++ks) {
        int arow = 16 * w + l15;
        int abyte = arow * 1024 + ((((ks * 32 + lk * 8) * 2)) ^ ((arow & 7) << 4));
        f16x8 aFrag = *(const f16x8*)((const char*)hLds + abyte);
        int krow = ks * 32 + lk * 8;
        #pragma unroll
        for (int ns = 0; ns < 8; ++ns) {
            int col = nt * 128 + ns * 16 + l15;
            f16x8 bFrag;
            if (col < VV) {
                #pragma unroll
                for (int i = 0; i < 8; ++i) bFrag[i] = (_Float16)Wd[(size_t)(krow + i) * VV + col];
            } else {
                #pragma unroll
                for (int i = 0; i < 8; ++i) bFrag[i] = (_Float16)0.f;
            }
            acc[ns] = __builtin_amdgcn_mfma_f32_16x16x32_f16(aFrag, bFrag, acc[ns], 0, 0, 0);
        }
    }

    float lg[8][4];
    float m[4] = {-3.4e38f, -3.4e38f, -3.4e38f, -3.4e38f};
    float ss[4] = {0.f, 0.f, 0.f, 0.f};
    #pragma unroll
    for (int ns = 0; ns < 8; ++ns) {
        int col = nt * 128 + ns * 16 + l15;
        bool ok = col < VV;
        float bv = ok ? bd[col] : 0.f;
        #pragma unroll
        for (int i = 0; i < 4; ++i) {
            int row = 16 * w + lk * 4 + i;
            float v = acc[ns][i] + bv;
            lg[ns][i] = ok ? v : -3.4e38f;
            if (ok) {
                out[(size_t)row * VV + col] = v;
                m[i] = fmaxf(m[i], v);
            }
        }
    }
    #pragma unroll
    for (int i = 0; i < 4; ++i) {
        #pragma unroll
        for (int ns = 0; ns < 8; ++ns)
            if (lg[ns][i] > -3.3e38f) ss[i] += __expf(lg[ns][i] - m[i]);
        for (int d = 1; d < 16; d <<= 1) {
            float m2 = __shfl_xor(m[i], d);
            float s2 = __shfl_xor(ss[i], d);
            float nM = fmaxf(m[i], m2);
            ss[i] = ss[i] * __expf(m[i] - nM) + s2 * __expf(m2 - nM);
            m[i] = nM;
        }
        if (l15 == 0) {
            int row = 16 * w + lk * 4 + i;
            partials[((size_t)nt * 64 + row) * 2 + 0] = m[i];
            partials[((size_t)nt * 64 + row) * 2 + 1] = ss[i];
        }
    }
}

__global__ __launch_bounds__(64) void k3_reduce(
    const float* __restrict__ partials, float* __restrict__ rowMS)
{
    int row = blockIdx.x, l = threadIdx.x;
    float M = -3.4e38f, Ssum = 0.f;
    for (int p = l; p < 393; p += 64) {
        float mp = partials[((size_t)p * 64 + row) * 2 + 0];
        float sp = partials[((size_t)p * 64 + row) * 2 + 1];
        float nM = fmaxf(M, mp);
        Ssum = Ssum * __expf(M - nM) + sp * __expf(mp - nM);
        M = nM;
    }
    for (int d = 1; d < 64; d <<= 1) {
        float m2 = __shfl_xor(M, d), s2 = __shfl_xor(Ssum, d);
        float nM = fmaxf(M, m2);
        Ssum = Ssum * __expf(M - nM) + s2 * __expf(m2 - nM);
        M = nM;
    }
    if (l == 0) { rowMS[row * 2] = M; rowMS[row * 2 + 1] = Ssum; }
}

__global__ __launch_bounds__(256) void k3_softmax(
    float* __restrict__ out, const float* __restrict__ rowMS)
{
    int col = blockIdx.x * 256 + threadIdx.x;
    int row = blockIdx.y;
    if (col < VV) {
        float M = rowMS[row * 2], Sv = rowMS[row * 2 + 1];
        size_t idx = (size_t)row * VV + col;
        out[idx] = __expf(out[idx] - M) / Sv;
    }
}

// ---------------------------------------------------------------------------
extern "C" void kernel_launch(void* const* d_in, const int* in_sizes, int n_in,
                              void* d_out, int out_size, void* d_ws, size_t ws_size,
                              hipStream_t stream) {
    const int*   tokens = (const int*)  d_in[0];
    const float* emb    = (const float*)d_in[1];
    const float* W      = (const float*)d_in[2];
    const float* U      = (const float*)d_in[3];
    const float* bias   = (const float*)d_in[4];
    const float* Wd     = (const float*)d_in[5];
    const float* bd     = (const float*)d_in[6];
    float* out = (float*)d_out;

    const size_t XP_BYTES   = (size_t)SS * BB * H3 * 2;     // 100,663,296
    const size_t WSU_BYTES  = (size_t)NWG * UBYTES;         // 1,589,248
    const size_t WSW_BYTES  = (size_t)32 * H3 * 8 * 2;      // 786,432
    const size_t HPUB_BYTES = 2 * (size_t)HBYTES;           // 131,072
    const size_t HLAST_BYTES= (size_t)BB * HH * 4;          // 131,072
    const size_t SYNC_BYTES = 4096;
    const size_t MASK_BYTES = (size_t)SS * 8;               // 4,096
    const size_t PART_BYTES = (size_t)393 * 64 * 2 * 4;     // 201,216

    char* ws = (char*)d_ws;
    _Float16* xp    = (_Float16*)ws;
    _Float16* wsU   = (_Float16*)(ws + XP_BYTES);
    _Float16* wsW   = (_Float16*)(ws + XP_BYTES + WSU_BYTES);
    char*     hpub  =            ws + XP_BYTES + WSU_BYTES + WSW_BYTES;
    float*    hlast = (float*)  (hpub + HPUB_BYTES);
    unsigned int* syncb = (unsigned int*)(hpub + HPUB_BYTES + HLAST_BYTES);
    unsigned long long* maskb = (unsigned long long*)(hpub + HPUB_BYTES + HLAST_BYTES + SYNC_BYTES);
    float* partials = (float*)(hpub + HPUB_BYTES + HLAST_BYTES + SYNC_BYTES + MASK_BYTES);
    float* rowMS    = (float*)(hpub + HPUB_BYTES + HLAST_BYTES + SYNC_BYTES + MASK_BYTES + PART_BYTES);

    hipFuncSetAttribute((const void*)k2_scan,
                        hipFuncAttributeMaxDynamicSharedMemorySize, UBYTES + HOUTB);

    kPackW<<<32 * H3 / 256, 256, 0, stream>>>(W, wsW);
    kPackU<<<NWG, 256, 0, stream>>>(U, wsU);
    kMask<<<2, 256, 0, stream>>>(tokens, maskb, syncb);
    k1_embed_proj<<<dim3(12, 512), 256, 0, stream>>>(tokens, emb, wsW, bias, xp);

    k2_scan<<<NLAUNCH, 256, UBYTES + HOUTB, stream>>>(xp, wsU, bias, maskb,
                                                      hpub, hlast, syncb);

    k3_logits<<<393, 256, 0, stream>>>(hlast, Wd, bd, out, partials);
    k3_reduce<<<64, 64, 0, stream>>>(partials, rowMS);
    k3_softmax<<<dim3((VV + 255) / 256, BB), 256, 0, stream>>>(out, rowMS);
}

// Round 9
// 4197.013 us; speedup vs baseline: 171.9248x; 171.9248x over previous
//
#include <hip/hip_runtime.h>
#include <hip/hip_bf16.h>

#define VV 50257
#define DD 256
#define HH 512
#define BB 64
#define SS 512
#define H3 1536
#define NWG 16          // scan workgroups
#define JSL 32          // hidden units per scan WG
#define UCPAD 97        // 96 cols (interleaved [z r h]x16 per ng) + 1 pad
#define UBYTES (64*UCPAD*16)   // 99328 B per-WG padded U slice image
#define HBYTES (BB*HH*2)       // 65536 B f16 h image, row-major [64][512]

typedef _Float16 f16x8 __attribute__((ext_vector_type(8)));
typedef _Float16 f16x4 __attribute__((ext_vector_type(4)));
typedef float f32x4 __attribute__((ext_vector_type(4)));
typedef unsigned int u32x4 __attribute__((ext_vector_type(4)));

#define AS1 __attribute__((address_space(1)))
#define AS3 __attribute__((address_space(3)))
#define GLL16(g, s) __builtin_amdgcn_global_load_lds((const AS1 char*)(g), (AS3 char*)(s), 16, 0, 0)

// ---------------------------------------------------------------------------
// Pack W (f32 [256][1536]) -> f16 k-major
// ---------------------------------------------------------------------------
__global__ __launch_bounds__(256) void kPackW(const float* __restrict__ W,
                                              _Float16* __restrict__ wsW) {
    int idx = blockIdx.x * 256 + threadIdx.x;     // 32 kb * 1536 col
    int kb = idx / H3, col = idx % H3;
    f16x8 v;
    #pragma unroll
    for (int e = 0; e < 8; ++e) v[e] = (_Float16)W[(size_t)(kb*8+e)*H3 + col];
    *(f16x8*)(wsW + (size_t)idx*8) = v;
}

// ---------------------------------------------------------------------------
// Pack U -> per-rank padded k-major images, gate-interleaved per 16-col block:
// packed col c (0..95): ng=c/48, g=(c%48)/16, jl=ng*16+(c%16)
// -> source col = g*512 + rank*32 + jl.   Row kb: 97 cols x 16B = 1552 B.
// ---------------------------------------------------------------------------
__global__ __launch_bounds__(256) void kPackU(const float* __restrict__ U,
                                              _Float16* __restrict__ wsU) {
    int wgp = blockIdx.x;                          // 16 ranks
    for (int idx = threadIdx.x; idx < 64*UCPAD; idx += 256) {
        int kb = idx / UCPAD, c = idx % UCPAD;
        int cc = (c == 96) ? 0 : c;
        int ng = cc / 48, rem = cc % 48;
        int g = rem / 16, jl = ng*16 + (rem % 16);
        int gcol = g*HH + wgp*JSL + jl;
        f16x8 v;
        #pragma unroll
        for (int e = 0; e < 8; ++e) v[e] = (_Float16)U[(size_t)(kb*8+e)*H3 + gcol];
        *(f16x8*)(wsU + (size_t)wgp*(UBYTES/2) + (size_t)idx*8) = v;
    }
}

// maskbits[t] bit r = (tokens[r][t] != 0); zero the 64 per-wave scan flags
__global__ __launch_bounds__(256) void kMask(const int* __restrict__ tokens,
                                             unsigned long long* __restrict__ mb,
                                             unsigned int* __restrict__ flags) {
    int t = blockIdx.x * 256 + threadIdx.x;
    if (t < SS) {
        unsigned long long m = 0ull;
        for (int r = 0; r < BB; ++r)
            m |= (unsigned long long)(tokens[r*SS + t] != 0) << r;
        mb[t] = m;
    }
    if (blockIdx.x == 0 && threadIdx.x < 64)
        __hip_atomic_store(flags + threadIdx.x * 16, 0u,
                           __ATOMIC_RELAXED, __HIP_MEMORY_SCOPE_AGENT);
}

// ---------------------------------------------------------------------------
// K1: xp[t][col][b] (f16) = (emb[tokens] @ W + b0)
// ---------------------------------------------------------------------------
__global__ __launch_bounds__(256) void k1_embed_proj(
    const int* __restrict__ tokens, const float* __restrict__ emb,
    const _Float16* __restrict__ wsW, const float* __restrict__ bias,
    _Float16* __restrict__ xp)
{
    const int s  = blockIdx.y;
    const int nt = blockIdx.x;
    const int tid = threadIdx.x;
    __shared__ _Float16 aLds[64 * 256];

    for (int c = tid; c < 64 * 32; c += 256) {
        int row = c >> 5, kc = c & 31;
        int tok = tokens[row * SS + s];
        const float* src = emb + (size_t)tok * DD + kc * 8;
        float4 f0 = *(const float4*)(src);
        float4 f1 = *(const float4*)(src + 4);
        f16x8 v;
        v[0]=(_Float16)f0.x; v[1]=(_Float16)f0.y; v[2]=(_Float16)f0.z; v[3]=(_Float16)f0.w;
        v[4]=(_Float16)f1.x; v[5]=(_Float16)f1.y; v[6]=(_Float16)f1.z; v[7]=(_Float16)f1.w;
        int byte = row * 512 + ((kc * 16) ^ ((row & 7) << 4));
        *(f16x8*)((char*)aLds + byte) = v;
    }
    __syncthreads();

    const int w = tid >> 6, l = tid & 63;
    const int l15 = l & 15, lk = l >> 4;
    const int colbase = nt * 128;
    f32x4 acc[8] = {};

    for (int ks = 0; ks < 8; ++ks) {
        int arow = 16 * w + l15;
        f16x8 aF = *(const f16x8*)((const char*)aLds + arow*512 + (((ks*32 + lk*8)*2) ^ ((arow & 7) << 4)));
        int kb = ks*4 + lk;
        #pragma unroll
        for (int ns = 0; ns < 8; ++ns) {
            int col = colbase + ns * 16 + l15;
            f16x8 bF = *(const f16x8*)(wsW + ((size_t)kb * H3 + col) * 8);
            acc[ns] = __builtin_amdgcn_mfma_f32_16x16x32_f16(aF, bF, acc[ns], 0, 0, 0);
        }
    }
    #pragma unroll
    for (int ns = 0; ns < 8; ++ns) {
        int col = colbase + ns * 16 + l15;
        float b0 = bias[col];
        f16x4 vv;
        #pragma unroll
        for (int i = 0; i < 4; ++i) vv[i] = (_Float16)(acc[ns][i] + b0);
        *(f16x4*)(xp + ((size_t)s * H3 + col) * BB + 16*w + lk*4) = vv;
    }
}

// ---------------------------------------------------------------------------
// K2: persistent GRU scan — barrier-free, per-wave flags, system-scope data.
// 16 WGs x 4 waves.  Wave (mg,ng) owns rows mg*32..+31, cols jg+ng*16..+15
// (x3 gates).  Per step, per wave: poll all 64 (rank,wave) flags (one per
// lane, s_sleep backoff) -> 32 system loads of h -> 48 MFMA -> gates ->
// 8 scattered system stores -> vmcnt(0) -> own flag++.  NO __syncthreads in
// the t-loop: wave skew is bounded at 1 step and publish-after-load ordering
// protects the double buffer.  t=0 skips h (h0=0) so hpub needs no init.
// ---------------------------------------------------------------------------
__global__ __launch_bounds__(256) void k2_scan(
    const _Float16* __restrict__ xp, const _Float16* __restrict__ wsU,
    const float* __restrict__ bias, const unsigned long long* __restrict__ maskbits,
    char* __restrict__ hpub, float* __restrict__ hlast,
    unsigned int* __restrict__ flags)
{
    extern __shared__ char uLds[];
    const int tid = threadIdx.x;
    const int rank = blockIdx.x;
    const int w = tid >> 6, l = tid & 63;
    const int l15 = l & 15, lk = l >> 4;
    const int mg = w >> 1, ng = w & 1;          // 2x2 wave split
    const int jg = rank * JSL;
    const int j  = jg + ng*16 + l15;            // this thread's hidden col

    // stage resident padded U slice (linear image -> linear LDS)
    {
        const char* src = (const char*)wsU + (size_t)rank * UBYTES;
        for (int base = 0; base < UBYTES; base += 4096) {
            int off = base + tid * 16;
            if (off < UBYTES) GLL16(src + off, uLds + off);
        }
    }
    const float b1z = bias[H3 + j];
    const float b1r = bias[H3 + HH + j];
    const float b1h = bias[H3 + 2*HH + j];
    float hold[2][4] = {};                      // [msub][i]
    __syncthreads();                            // U staged (only barrier)

    for (int t = 0; t < SS; ++t) {
        // gate-phase xp loads (issue before the wait; cold HBM hides here)
        const _Float16* xpt = xp + (size_t)t * H3 * BB;
        const int b0 = mg*32 + lk*4;
        f16x4 xz0 = *(const f16x4*)(xpt + (0*HH + j)*BB + b0);
        f16x4 xz1 = *(const f16x4*)(xpt + (0*HH + j)*BB + b0 + 16);
        f16x4 xr0 = *(const f16x4*)(xpt + (1*HH + j)*BB + b0);
        f16x4 xr1 = *(const f16x4*)(xpt + (1*HH + j)*BB + b0 + 16);
        f16x4 xh0 = *(const f16x4*)(xpt + (2*HH + j)*BB + b0);
        f16x4 xh1 = *(const f16x4*)(xpt + (2*HH + j)*BB + b0 + 16);
        unsigned long long mb = maskbits[t];

        f32x4 az0 = {}, az1 = {}, ar0 = {}, ar1 = {}, ah0 = {}, ah1 = {};

        if (t > 0) {
            // every wave polls all 64 per-wave flags: lane l <-> flag l
            {
                const unsigned int* fp = flags + l * 16;
                unsigned v; int n = 0;
                do {
                    v = __hip_atomic_load(fp, __ATOMIC_RELAXED, __HIP_MEMORY_SCOPE_AGENT);
                    if (v >= (unsigned)t) break;
                    if (++n > 64) __builtin_amdgcn_s_sleep(1);
                } while (n < 50000);
            }

            // A-fragments: rows mg*32 + {0,16} + l15, 16 ks x 16B, system loads
            const char* hsrc = hpub + (size_t)(t & 1) * HBYTES;
            unsigned long long hb0 = (unsigned long long)(hsrc + (mg*32 + l15)*1024 + lk*16);
            unsigned long long hb1 = hb0 + 16*1024;
            u32x4 hf0[16], hf1[16];
#define LDH(arr, base, i, off) asm volatile("global_load_dwordx4 %0, %1, off offset:" off " sc0 sc1" \
                                 : "=v"(arr[i]) : "v"(base) : "memory")
            LDH(hf0,hb0,0,"0");    LDH(hf0,hb0,1,"64");   LDH(hf0,hb0,2,"128");  LDH(hf0,hb0,3,"192");
            LDH(hf0,hb0,4,"256");  LDH(hf0,hb0,5,"320");  LDH(hf0,hb0,6,"384");  LDH(hf0,hb0,7,"448");
            LDH(hf0,hb0,8,"512");  LDH(hf0,hb0,9,"576");  LDH(hf0,hb0,10,"640"); LDH(hf0,hb0,11,"704");
            LDH(hf0,hb0,12,"768"); LDH(hf0,hb0,13,"832"); LDH(hf0,hb0,14,"896"); LDH(hf0,hb0,15,"960");
            LDH(hf1,hb1,0,"0");    LDH(hf1,hb1,1,"64");   LDH(hf1,hb1,2,"128");  LDH(hf1,hb1,3,"192");
            LDH(hf1,hb1,4,"256");  LDH(hf1,hb1,5,"320");  LDH(hf1,hb1,6,"384");  LDH(hf1,hb1,7,"448");
            LDH(hf1,hb1,8,"512");  LDH(hf1,hb1,9,"576");  LDH(hf1,hb1,10,"640"); LDH(hf1,hb1,11,"704");
            LDH(hf1,hb1,12,"768"); LDH(hf1,hb1,13,"832"); LDH(hf1,hb1,14,"896"); LDH(hf1,hb1,15,"960");
#undef LDH
            asm volatile("s_waitcnt vmcnt(0)" ::: "memory");
            __builtin_amdgcn_sched_barrier(0);

            // rec = h @ Uslice : 2 m-subtiles x 3 gates (this wave's 16 cols)
            #pragma unroll
            for (int ks = 0; ks < 16; ++ks) {
                f16x8 a0 = __builtin_bit_cast(f16x8, hf0[ks]);
                f16x8 a1 = __builtin_bit_cast(f16x8, hf1[ks]);
                const char* ub = uLds + (size_t)(ks*4 + lk) * (UCPAD*16) + ng*768 + l15*16;
                f16x8 bz = *(const f16x8*)(ub);
                f16x8 br = *(const f16x8*)(ub + 256);
                f16x8 bh = *(const f16x8*)(ub + 512);
                az0 = __builtin_amdgcn_mfma_f32_16x16x32_f16(a0, bz, az0, 0, 0, 0);
                az1 = __builtin_amdgcn_mfma_f32_16x16x32_f16(a1, bz, az1, 0, 0, 0);
                ar0 = __builtin_amdgcn_mfma_f32_16x16x32_f16(a0, br, ar0, 0, 0, 0);
                ar1 = __builtin_amdgcn_mfma_f32_16x16x32_f16(a1, br, ar1, 0, 0, 0);
                ah0 = __builtin_amdgcn_mfma_f32_16x16x32_f16(a0, bh, ah0, 0, 0, 0);
                ah1 = __builtin_amdgcn_mfma_f32_16x16x32_f16(a1, bh, ah1, 0, 0, 0);
            }
        }

        // gates
        _Float16 hv[2][4];
        #pragma unroll
        for (int ms = 0; ms < 2; ++ms) {
            f32x4 az = ms ? az1 : az0;
            f32x4 ar = ms ? ar1 : ar0;
            f32x4 ah = ms ? ah1 : ah0;
            f16x4 xz = ms ? xz1 : xz0;
            f16x4 xr = ms ? xr1 : xr0;
            f16x4 xh = ms ? xh1 : xh0;
            #pragma unroll
            for (int i = 0; i < 4; ++i) {
                int row = mg*32 + ms*16 + lk*4 + i;
                float z  = 1.f / (1.f + __expf(-((float)xz[i] + az[i] + b1z)));
                float rg = 1.f / (1.f + __expf(-((float)xr[i] + ar[i] + b1r)));
                float ag = (float)xh[i] + rg * (ah[i] + b1h);
                float hc = 1.f - 2.f / (__expf(2.f * ag) + 1.f);
                float hn = z * hold[ms][i] + (1.f - z) * hc;
                if (!((mb >> row) & 1ull)) hn = hold[ms][i];
                hold[ms][i] = hn;
                hv[ms][i] = (_Float16)hn;
            }
        }

        if (t < SS - 1) {
            // scattered system-scope publish: 8 x 2B stores, two base regs
            // (13-bit signed offset limit: keep immediates <= 3072)
            char* hnxt = hpub + (size_t)((t+1) & 1) * HBYTES;
            unsigned long long ha0 = (unsigned long long)
                (hnxt + (mg*32 + lk*4)*1024 + (size_t)j*2);
            unsigned long long ha1 = ha0 + 16*1024;
#define PUBH(base, v16, off) asm volatile("global_store_short %0, %1, off offset:" off " sc0 sc1" \
                                    :: "v"(base), "v"((unsigned int)__builtin_bit_cast(unsigned short, v16)) : "memory")
            PUBH(ha0, hv[0][0], "0");     PUBH(ha0, hv[0][1], "1024");
            PUBH(ha0, hv[0][2], "2048");  PUBH(ha0, hv[0][3], "3072");
            PUBH(ha1, hv[1][0], "0");     PUBH(ha1, hv[1][1], "1024");
            PUBH(ha1, hv[1][2], "2048");  PUBH(ha1, hv[1][3], "3072");
#undef PUBH
            asm volatile("s_waitcnt vmcnt(0)" ::: "memory");
            if (l == 0)
                __hip_atomic_store(flags + (rank*4 + w) * 16, (unsigned)(t + 1),
                                   __ATOMIC_RELAXED, __HIP_MEMORY_SCOPE_AGENT);
        } else {
            #pragma unroll
            for (int ms = 0; ms < 2; ++ms)
                #pragma unroll
                for (int i = 0; i < 4; ++i) {
                    int row = mg*32 + ms*16 + lk*4 + i;
                    hlast[row*HH + j] = hold[ms][i];
                }
        }
    }
}

// ---------------------------------------------------------------------------
// K3a: logits + per-WG softmax partials
// ---------------------------------------------------------------------------
__global__ __launch_bounds__(256) void k3_logits(
    const float* __restrict__ hin, const float* __restrict__ Wd,
    const float* __restrict__ bd, float* __restrict__ out,
    float* __restrict__ partials)
{
    const int nt = blockIdx.x;
    const int tid = threadIdx.x;
    __shared__ _Float16 hLds[64 * 512];

    for (int c = tid; c < 64 * 64; c += 256) {
        int row = c >> 6, kc = c & 63;
        const float* src = hin + row * HH + kc * 8;
        float4 f0 = *(const float4*)(src);
        float4 f1 = *(const float4*)(src + 4);
        f16x8 v;
        v[0]=(_Float16)f0.x; v[1]=(_Float16)f0.y; v[2]=(_Float16)f0.z; v[3]=(_Float16)f0.w;
        v[4]=(_Float16)f1.x; v[5]=(_Float16)f1.y; v[6]=(_Float16)f1.z; v[7]=(_Float16)f1.w;
        int byte = row * 1024 + ((kc * 16) ^ ((row & 7) << 4));
        *(f16x8*)((char*)hLds + byte) = v;
    }
    __syncthreads();

    const int w = tid >> 6, l = tid & 63;
    const int l15 = l & 15, lk = l >> 4;
    f32x4 acc[8] = {};

    for (int ks = 0; ks < 16; ++ks) {
        int arow = 16 * w + l15;
        int abyte = arow * 1024 + ((((ks * 32 + lk * 8) * 2)) ^ ((arow & 7) << 4));
        f16x8 aFrag = *(const f16x8*)((const char*)hLds + abyte);
        int krow = ks * 32 + lk * 8;
        #pragma unroll
        for (int ns = 0; ns < 8; ++ns) {
            int col = nt * 128 + ns * 16 + l15;
            f16x8 bFrag;
            if (col < VV) {
                #pragma unroll
                for (int i = 0; i < 8; ++i) bFrag[i] = (_Float16)Wd[(size_t)(krow + i) * VV + col];
            } else {
                #pragma unroll
                for (int i = 0; i < 8; ++i) bFrag[i] = (_Float16)0.f;
            }
            acc[ns] = __builtin_amdgcn_mfma_f32_16x16x32_f16(aFrag, bFrag, acc[ns], 0, 0, 0);
        }
    }

    float lg[8][4];
    float m[4] = {-3.4e38f, -3.4e38f, -3.4e38f, -3.4e38f};
    float ss[4] = {0.f, 0.f, 0.f, 0.f};
    #pragma unroll
    for (int ns = 0; ns < 8; ++ns) {
        int col = nt * 128 + ns * 16 + l15;
        bool ok = col < VV;
        float bv = ok ? bd[col] : 0.f;
        #pragma unroll
        for (int i = 0; i < 4; ++i) {
            int row = 16 * w + lk * 4 + i;
            float v = acc[ns][i] + bv;
            lg[ns][i] = ok ? v : -3.4e38f;
            if (ok) {
                out[(size_t)row * VV + col] = v;
                m[i] = fmaxf(m[i], v);
            }
        }
    }
    #pragma unroll
    for (int i = 0; i < 4; ++i) {
        #pragma unroll
        for (int ns = 0; ns < 8; ++ns)
            if (lg[ns][i] > -3.3e38f) ss[i] += __expf(lg[ns][i] - m[i]);
        for (int d = 1; d < 16; d <<= 1) {
            float m2 = __shfl_xor(m[i], d);
            float s2 = __shfl_xor(ss[i], d);
            float nM = fmaxf(m[i], m2);
            ss[i] = ss[i] * __expf(m[i] - nM) + s2 * __expf(m2 - nM);
            m[i] = nM;
        }
        if (l15 == 0) {
            int row = 16 * w + lk * 4 + i;
            partials[((size_t)nt * 64 + row) * 2 + 0] = m[i];
            partials[((size_t)nt * 64 + row) * 2 + 1] = ss[i];
        }
    }
}

__global__ __launch_bounds__(64) void k3_reduce(
    const float* __restrict__ partials, float* __restrict__ rowMS)
{
    int row = blockIdx.x, l = threadIdx.x;
    float M = -3.4e38f, Ssum = 0.f;
    for (int p = l; p < 393; p += 64) {
        float mp = partials[((size_t)p * 64 + row) * 2 + 0];
        float sp = partials[((size_t)p * 64 + row) * 2 + 1];
        float nM = fmaxf(M, mp);
        Ssum = Ssum * __expf(M - nM) + sp * __expf(mp - nM);
        M = nM;
    }
    for (int d = 1; d < 64; d <<= 1) {
        float m2 = __shfl_xor(M, d), s2 = __shfl_xor(Ssum, d);
        float nM = fmaxf(M, m2);
        Ssum = Ssum * __expf(M - nM) + s2 * __expf(m2 - nM);
        M = nM;
    }
    if (l == 0) { rowMS[row * 2] = M; rowMS[row * 2 + 1] = Ssum; }
}

__global__ __launch_bounds__(256) void k3_softmax(
    float* __restrict__ out, const float* __restrict__ rowMS)
{
    int col = blockIdx.x * 256 + threadIdx.x;
    int row = blockIdx.y;
    if (col < VV) {
        float M = rowMS[row * 2], Sv = rowMS[row * 2 + 1];
        size_t idx = (size_t)row * VV + col;
        out[idx] = __expf(out[idx] - M) / Sv;
    }
}

// ---------------------------------------------------------------------------
extern "C" void kernel_launch(void* const* d_in, const int* in_sizes, int n_in,
                              void* d_out, int out_size, void* d_ws, size_t ws_size,
                              hipStream_t stream) {
    const int*   tokens = (const int*)  d_in[0];
    const float* emb    = (const float*)d_in[1];
    const float* W      = (const float*)d_in[2];
    const float* U      = (const float*)d_in[3];
    const float* bias   = (const float*)d_in[4];
    const float* Wd     = (const float*)d_in[5];
    const float* bd     = (const float*)d_in[6];
    float* out = (float*)d_out;

    const size_t XP_BYTES   = (size_t)SS * BB * H3 * 2;     // 100,663,296
    const size_t WSU_BYTES  = (size_t)NWG * UBYTES;         // 1,589,248
    const size_t WSW_BYTES  = (size_t)32 * H3 * 8 * 2;      // 786,432
    const size_t HPUB_BYTES = 2 * (size_t)HBYTES;           // 131,072
    const size_t HLAST_BYTES= (size_t)BB * HH * 4;          // 131,072
    const size_t SYNC_BYTES = 8192;
    const size_t MASK_BYTES = (size_t)SS * 8;               // 4,096
    const size_t PART_BYTES = (size_t)393 * 64 * 2 * 4;     // 201,216

    char* ws = (char*)d_ws;
    _Float16* xp    = (_Float16*)ws;
    _Float16* wsU   = (_Float16*)(ws + XP_BYTES);
    _Float16* wsW   = (_Float16*)(ws + XP_BYTES + WSU_BYTES);
    char*     hpub  =            ws + XP_BYTES + WSU_BYTES + WSW_BYTES;
    float*    hlast = (float*)  (hpub + HPUB_BYTES);
    unsigned int* syncb = (unsigned int*)(hpub + HPUB_BYTES + HLAST_BYTES);
    unsigned long long* maskb = (unsigned long long*)(hpub + HPUB_BYTES + HLAST_BYTES + SYNC_BYTES);
    float* partials = (float*)(hpub + HPUB_BYTES + HLAST_BYTES + SYNC_BYTES + MASK_BYTES);
    float* rowMS    = (float*)(hpub + HPUB_BYTES + HLAST_BYTES + SYNC_BYTES + MASK_BYTES + PART_BYTES);

    hipFuncSetAttribute((const void*)k2_scan,
                        hipFuncAttributeMaxDynamicSharedMemorySize, UBYTES);

    kPackW<<<32 * H3 / 256, 256, 0, stream>>>(W, wsW);
    kPackU<<<NWG, 256, 0, stream>>>(U, wsU);
    kMask<<<2, 256, 0, stream>>>(tokens, maskb, syncb);
    k1_embed_proj<<<dim3(12, 512), 256, 0, stream>>>(tokens, emb, wsW, bias, xp);

    k2_scan<<<NWG, 256, UBYTES, stream>>>(xp, wsU, bias, maskb,
                                          hpub, hlast, syncb);

    k3_logits<<<393, 256, 0, stream>>>(hlast, Wd, bd, out, partials);
    k3_reduce<<<64, 64, 0, stream>>>(partials, rowMS);
    k3_softmax<<<dim3((VV + 255) / 256, BB), 256, 0, stream>>>(out, rowMS);
}

// Round 10
// 3185.797 us; speedup vs baseline: 226.4961x; 1.3174x over previous
//
#include <hip/hip_runtime.h>
#include <hip/hip_bf16.h>

#define VV 50257
#define DD 256
#define HH 512
#define BB 64
#define SS 512
#define H3 1536
#define NWG 32          // scan workgroups (16 hidden units each)
#define JSL 16
#define UCOLS 48        // 3 gates x 16
#define UBYTES (64*UCOLS*16)   // 49152 B resident U slice
#define HBYTES (BB*HH*2)       // 65536 B f16 h image [64][512]

typedef _Float16 f16x8 __attribute__((ext_vector_type(8)));
typedef _Float16 f16x4 __attribute__((ext_vector_type(4)));
typedef float f32x4 __attribute__((ext_vector_type(4)));
typedef unsigned int u32x4 __attribute__((ext_vector_type(4)));

#define AS1 __attribute__((address_space(1)))
#define AS3 __attribute__((address_space(3)))
#define GLL16(g, s) __builtin_amdgcn_global_load_lds((const AS1 char*)(g), (AS3 char*)(s), 16, 0, 0)

// ---------------------------------------------------------------------------
// Pack W (f32 [256][1536]) -> f16 k-major
// ---------------------------------------------------------------------------
__global__ __launch_bounds__(256) void kPackW(const float* __restrict__ W,
                                              _Float16* __restrict__ wsW) {
    int idx = blockIdx.x * 256 + threadIdx.x;
    int kb = idx / H3, col = idx % H3;
    f16x8 v;
    #pragma unroll
    for (int e = 0; e < 8; ++e) v[e] = (_Float16)W[(size_t)(kb*8+e)*H3 + col];
    *(f16x8*)(wsW + (size_t)idx*8) = v;
}

// ---------------------------------------------------------------------------
// Pack U -> per-rank k-major images (rank r: cols {g*512 + r*16 + jl})
// ---------------------------------------------------------------------------
__global__ __launch_bounds__(256) void kPackU(const float* __restrict__ U,
                                              _Float16* __restrict__ wsU) {
    int wgp = blockIdx.x;                          // 32 ranks
    for (int idx = threadIdx.x; idx < 64*UCOLS; idx += 256) {
        int kb = idx / UCOLS, c = idx % UCOLS;
        int g = c / JSL, jl = c % JSL;
        int gcol = g*HH + wgp*JSL + jl;
        f16x8 v;
        #pragma unroll
        for (int e = 0; e < 8; ++e) v[e] = (_Float16)U[(size_t)(kb*8+e)*H3 + gcol];
        *(f16x8*)(wsU + (size_t)wgp*(UBYTES/2) + (size_t)idx*8) = v;
    }
}

// maskbits[t] bit r = (tokens[r][t] != 0)
__global__ __launch_bounds__(256) void kMask(const int* __restrict__ tokens,
                                             unsigned long long* __restrict__ mb) {
    int t = blockIdx.x * 256 + threadIdx.x;
    if (t < SS) {
        unsigned long long m = 0ull;
        for (int r = 0; r < BB; ++r)
            m |= (unsigned long long)(tokens[r*SS + t] != 0) << r;
        mb[t] = m;
    }
}

// ---------------------------------------------------------------------------
// K1: xp[t][col][b] (f16) = (emb[tokens] @ W + b0)
// ---------------------------------------------------------------------------
__global__ __launch_bounds__(256) void k1_embed_proj(
    const int* __restrict__ tokens, const float* __restrict__ emb,
    const _Float16* __restrict__ wsW, const float* __restrict__ bias,
    _Float16* __restrict__ xp)
{
    const int s  = blockIdx.y;
    const int nt = blockIdx.x;
    const int tid = threadIdx.x;
    __shared__ _Float16 aLds[64 * 256];

    for (int c = tid; c < 64 * 32; c += 256) {
        int row = c >> 5, kc = c & 31;
        int tok = tokens[row * SS + s];
        const float* src = emb + (size_t)tok * DD + kc * 8;
        float4 f0 = *(const float4*)(src);
        float4 f1 = *(const float4*)(src + 4);
        f16x8 v;
        v[0]=(_Float16)f0.x; v[1]=(_Float16)f0.y; v[2]=(_Float16)f0.z; v[3]=(_Float16)f0.w;
        v[4]=(_Float16)f1.x; v[5]=(_Float16)f1.y; v[6]=(_Float16)f1.z; v[7]=(_Float16)f1.w;
        int byte = row * 512 + ((kc * 16) ^ ((row & 7) << 4));
        *(f16x8*)((char*)aLds + byte) = v;
    }
    __syncthreads();

    const int w = tid >> 6, l = tid & 63;
    const int l15 = l & 15, lk = l >> 4;
    const int colbase = nt * 128;
    f32x4 acc[8] = {};

    for (int ks = 0; ks < 8; ++ks) {
        int arow = 16 * w + l15;
        f16x8 aF = *(const f16x8*)((const char*)aLds + arow*512 + (((ks*32 + lk*8)*2) ^ ((arow & 7) << 4)));
        int kb = ks*4 + lk;
        #pragma unroll
        for (int ns = 0; ns < 8; ++ns) {
            int col = colbase + ns * 16 + l15;
            f16x8 bF = *(const f16x8*)(wsW + ((size_t)kb * H3 + col) * 8);
            acc[ns] = __builtin_amdgcn_mfma_f32_16x16x32_f16(aF, bF, acc[ns], 0, 0, 0);
        }
    }
    #pragma unroll
    for (int ns = 0; ns < 8; ++ns) {
        int col = colbase + ns * 16 + l15;
        float b0 = bias[col];
        f16x4 vv;
        #pragma unroll
        for (int i = 0; i < 4; ++i) vv[i] = (_Float16)(acc[ns][i] + b0);
        *(f16x4*)(xp + ((size_t)s * H3 + col) * BB + 16*w + lk*4) = vv;
    }
}

// ---------------------------------------------------------------------------
// K2: persistent GRU scan — in-band parity tags, zero flags, zero barriers.
// |h|<1 strictly => f16 bit14 == 0 always; publish h with bit14 = step tag
// ((t+1)>>1)&1 into buffer (t+1)&1.  Consumers poll their own A-packets
// (16 x dwordx4 sc0sc1) until all 8 values per packet carry the expected
// tag, strip bit14, MFMA.  Publishes are fire-and-forget (self-poll next
// step bounds staleness; dataflow bounds skew to 1 step per 16-row band).
// xp/mask prefetched 2 steps ahead (even/odd register slots).
// ---------------------------------------------------------------------------
__global__ __launch_bounds__(256) void k2_scan(
    const _Float16* __restrict__ xp, const _Float16* __restrict__ wsU,
    const float* __restrict__ bias, const unsigned long long* __restrict__ maskbits,
    char* __restrict__ hpub, float* __restrict__ hlast)
{
    extern __shared__ char uLds[];
    const int tid = threadIdx.x;
    const int rank = blockIdx.x;
    const int w = tid >> 6, l = tid & 63;
    const int l15 = l & 15, lk = l >> 4;
    const int jg = rank * JSL;
    const int j  = jg + l15;
    const int b0 = w*16 + lk*4;

    // stage resident U slice (12 x 4KB)
    {
        const char* src = (const char*)wsU + (size_t)rank * UBYTES;
        #pragma unroll
        for (int base = 0; base < UBYTES; base += 4096)
            GLL16(src + base + tid*16, uLds + base + tid*16);
    }

    // prologue prefetch: xp(0) -> even slot, xp(1) -> odd slot
    f16x4 xpe0, xpe1, xpe2, xpo0, xpo1, xpo2;
    unsigned long long mbe, mbo;
    {
        const _Float16* x0 = xp;
        xpe0 = *(const f16x4*)(x0 + (0*HH + j)*BB + b0);
        xpe1 = *(const f16x4*)(x0 + (1*HH + j)*BB + b0);
        xpe2 = *(const f16x4*)(x0 + (2*HH + j)*BB + b0);
        const _Float16* x1 = xp + (size_t)H3 * BB;
        xpo0 = *(const f16x4*)(x1 + (0*HH + j)*BB + b0);
        xpo1 = *(const f16x4*)(x1 + (1*HH + j)*BB + b0);
        xpo2 = *(const f16x4*)(x1 + (2*HH + j)*BB + b0);
        mbe = maskbits[0];
        mbo = maskbits[1];
    }
    const float b1z = bias[H3 + j];
    const float b1r = bias[H3 + HH + j];
    const float b1h = bias[H3 + 2*HH + j];
    float hold[4] = {};
    __syncthreads();   // U staged (only barrier in kernel)

    auto step = [&](int t, f16x4 xz4, f16x4 xr4, f16x4 xh4,
                    unsigned long long mbv) __attribute__((always_inline)) {
        f32x4 az = {}, ar = {}, ah = {};
        if (t > 0) {
            const unsigned expm = ((t >> 1) & 1) ? 0x40004000u : 0u;
            const char* hsrc = hpub + (size_t)(t & 1) * HBYTES;
            unsigned long long hb = (unsigned long long)(hsrc + (w*16 + l15)*1024 + lk*16);
            u32x4 hf[16];
            int n = 0;
            while (true) {
#define LDH(i, off) asm volatile("global_load_dwordx4 %0, %1, off offset:" off " sc0 sc1" \
                                 : "=v"(hf[i]) : "v"(hb) : "memory")
                LDH(0,"0");    LDH(1,"64");   LDH(2,"128");  LDH(3,"192");
                LDH(4,"256");  LDH(5,"320");  LDH(6,"384");  LDH(7,"448");
                LDH(8,"512");  LDH(9,"576");  LDH(10,"640"); LDH(11,"704");
                LDH(12,"768"); LDH(13,"832"); LDH(14,"896"); LDH(15,"960");
#undef LDH
                asm volatile("s_waitcnt vmcnt(0)" ::: "memory");
                __builtin_amdgcn_sched_barrier(0);
                unsigned st = 0;
                #pragma unroll
                for (int p = 0; p < 16; ++p) {
                    #pragma unroll
                    for (int d = 0; d < 4; ++d)
                        st |= (hf[p][d] & 0x40004000u) ^ expm;
                }
                if (!__any((int)(st != 0))) break;
                if (++n > 2000) break;   // fast-fail bound
            }
            // strip tags -> clean f16 A-fragments
            #pragma unroll
            for (int p = 0; p < 16; ++p) {
                #pragma unroll
                for (int d = 0; d < 4; ++d) hf[p][d] &= 0xBFFFBFFFu;
            }
            __builtin_amdgcn_sched_barrier(0);
            #pragma unroll
            for (int ks = 0; ks < 16; ++ks) {
                f16x8 a = __builtin_bit_cast(f16x8, hf[ks]);
                const char* ub = uLds + (size_t)(ks*4 + lk) * (UCOLS*16) + l15*16;
                f16x8 bz = *(const f16x8*)(ub);
                f16x8 br = *(const f16x8*)(ub + 256);
                f16x8 bh = *(const f16x8*)(ub + 512);
                az = __builtin_amdgcn_mfma_f32_16x16x32_f16(a, bz, az, 0, 0, 0);
                ar = __builtin_amdgcn_mfma_f32_16x16x32_f16(a, br, ar, 0, 0, 0);
                ah = __builtin_amdgcn_mfma_f32_16x16x32_f16(a, bh, ah, 0, 0, 0);
            }
        }
        // gates
        unsigned hv[4];
        #pragma unroll
        for (int i = 0; i < 4; ++i) {
            int row = b0 + i;
            float z  = 1.f / (1.f + __expf(-((float)xz4[i] + az[i] + b1z)));
            float rg = 1.f / (1.f + __expf(-((float)xr4[i] + ar[i] + b1r)));
            float ag = (float)xh4[i] + rg * (ah[i] + b1h);
            float hc = 1.f - 2.f / (__expf(2.f * ag) + 1.f);
            float hn = z * hold[i] + (1.f - z) * hc;
            if (!((mbv >> row) & 1ull)) hn = hold[i];
            hold[i] = hn;
            unsigned hb16 = (unsigned)__builtin_bit_cast(unsigned short, (_Float16)hn);
            if ((hb16 & 0x7FFFu) >= 0x3C00u) hb16 = (hb16 & 0x8000u) | 0x3BFFu;  // |h|>=1 guard
            hv[i] = hb16;
        }
        if (t < SS - 1) {
            unsigned tg = (((unsigned)(t + 1) >> 1) & 1u) << 14;
            char* hnxt = hpub + (size_t)((t + 1) & 1) * HBYTES;
            unsigned long long ha = (unsigned long long)(hnxt + (size_t)b0*1024 + (size_t)j*2);
#define PUBH(vv, off) asm volatile("global_store_short %0, %1, off offset:" off " sc0 sc1" \
                                   :: "v"(ha), "v"(vv) : "memory")
            PUBH(hv[0] | tg, "0");
            PUBH(hv[1] | tg, "1024");
            PUBH(hv[2] | tg, "2048");
            PUBH(hv[3] | tg, "3072");
#undef PUBH
        } else {
            #pragma unroll
            for (int i = 0; i < 4; ++i)
                hlast[(b0 + i)*HH + j] = hold[i];
        }
    };

    for (int t = 0; t < SS; t += 2) {
        step(t, xpe0, xpe1, xpe2, mbe);
        {   // prefetch even slot <- t+2
            int tl = (t + 2 < SS) ? t + 2 : SS - 1;
            const _Float16* xt = xp + (size_t)tl * H3 * BB;
            xpe0 = *(const f16x4*)(xt + (0*HH + j)*BB + b0);
            xpe1 = *(const f16x4*)(xt + (1*HH + j)*BB + b0);
            xpe2 = *(const f16x4*)(xt + (2*HH + j)*BB + b0);
            mbe = maskbits[tl];
        }
        step(t + 1, xpo0, xpo1, xpo2, mbo);
        {   // prefetch odd slot <- t+3
            int tl = (t + 3 < SS) ? t + 3 : SS - 1;
            const _Float16* xt = xp + (size_t)tl * H3 * BB;
            xpo0 = *(const f16x4*)(xt + (0*HH + j)*BB + b0);
            xpo1 = *(const f16x4*)(xt + (1*HH + j)*BB + b0);
            xpo2 = *(const f16x4*)(xt + (2*HH + j)*BB + b0);
            mbo = maskbits[tl];
        }
    }
}

// ---------------------------------------------------------------------------
// K3a: logits + per-WG softmax partials
// ---------------------------------------------------------------------------
__global__ __launch_bounds__(256) void k3_logits(
    const float* __restrict__ hin, const float* __restrict__ Wd,
    const float* __restrict__ bd, float* __restrict__ out,
    float* __restrict__ partials)
{
    const int nt = blockIdx.x;
    const int tid = threadIdx.x;
    __shared__ _Float16 hLds[64 * 512];

    for (int c = tid; c < 64 * 64; c += 256) {
        int row = c >> 6, kc = c & 63;
        const float* src = hin + row * HH + kc * 8;
        float4 f0 = *(const float4*)(src);
        float4 f1 = *(const float4*)(src + 4);
        f16x8 v;
        v[0]=(_Float16)f0.x; v[1]=(_Float16)f0.y; v[2]=(_Float16)f0.z; v[3]=(_Float16)f0.w;
        v[4]=(_Float16)f1.x; v[5]=(_Float16)f1.y; v[6]=(_Float16)f1.z; v[7]=(_Float16)f1.w;
        int byte = row * 1024 + ((kc * 16) ^ ((row & 7) << 4));
        *(f16x8*)((char*)hLds + byte) = v;
    }
    __syncthreads();

    const int w = tid >> 6, l = tid & 63;
    const int l15 = l & 15, lk = l >> 4;
    f32x4 acc[8] = {};

    for (int ks = 0; ks < 16; ++ks) {
        int arow = 16 * w + l15;
        int abyte = arow * 1024 + ((((ks * 32 + lk * 8) * 2)) ^ ((arow & 7) << 4));
        f16x8 aFrag = *(const f16x8*)((const char*)hLds + abyte);
        int krow = ks * 32 + lk * 8;
        #pragma unroll
        for (int ns = 0; ns < 8; ++ns) {
            int col = nt * 128 + ns * 16 + l15;
            f16x8 bFrag;
            if (col < VV) {
                #pragma unroll
                for (int i = 0; i < 8; ++i) bFrag[i] = (_Float16)Wd[(size_t)(krow + i) * VV + col];
            } else {
                #pragma unroll
                for (int i = 0; i < 8; ++i) bFrag[i] = (_Float16)0.f;
            }
            acc[ns] = __builtin_amdgcn_mfma_f32_16x16x32_f16(aFrag, bFrag, acc[ns], 0, 0, 0);
        }
    }

    float lg[8][4];
    float m[4] = {-3.4e38f, -3.4e38f, -3.4e38f, -3.4e38f};
    float ss[4] = {0.f, 0.f, 0.f, 0.f};
    #pragma unroll
    for (int ns = 0; ns < 8; ++ns) {
        int col = nt * 128 + ns * 16 + l15;
        bool ok = col < VV;
        float bv = ok ? bd[col] : 0.f;
        #pragma unroll
        for (int i = 0; i < 4; ++i) {
            int row = 16 * w + lk * 4 + i;
            float v = acc[ns][i] + bv;
            lg[ns][i] = ok ? v : -3.4e38f;
            if (ok) {
                out[(size_t)row * VV + col] = v;
                m[i] = fmaxf(m[i], v);
            }
        }
    }
    #pragma unroll
    for (int i = 0; i < 4; ++i) {
        #pragma unroll
        for (int ns = 0; ns < 8; ++ns)
            if (lg[ns][i] > -3.3e38f) ss[i] += __expf(lg[ns][i] - m[i]);
        for (int d = 1; d < 16; d <<= 1) {
            float m2 = __shfl_xor(m[i], d);
            float s2 = __shfl_xor(ss[i], d);
            float nM = fmaxf(m[i], m2);
            ss[i] = ss[i] * __expf(m[i] - nM) + s2 * __expf(m2 - nM);
            m[i] = nM;
        }
        if (l15 == 0) {
            int row = 16 * w + lk * 4 + i;
            partials[((size_t)nt * 64 + row) * 2 + 0] = m[i];
            partials[((size_t)nt * 64 + row) * 2 + 1] = ss[i];
        }
    }
}

__global__ __launch_bounds__(64) void k3_reduce(
    const float* __restrict__ partials, float* __restrict__ rowMS)
{
    int row = blockIdx.x, l = threadIdx.x;
    float M = -3.4e38f, Ssum = 0.f;
    for (int p = l; p < 393; p += 64) {
        float mp = partials[((size_t)p * 64 + row) * 2 + 0];
        float sp = partials[((size_t)p * 64 + row) * 2 + 1];
        float nM = fmaxf(M, mp);
        Ssum = Ssum * __expf(M - nM) + sp * __expf(mp - nM);
        M = nM;
    }
    for (int d = 1; d < 64; d <<= 1) {
        float m2 = __shfl_xor(M, d), s2 = __shfl_xor(Ssum, d);
        float nM = fmaxf(M, m2);
        Ssum = Ssum * __expf(M - nM) + s2 * __expf(m2 - nM);
        M = nM;
    }
    if (l == 0) { rowMS[row * 2] = M; rowMS[row * 2 + 1] = Ssum; }
}

__global__ __launch_bounds__(256) void k3_softmax(
    float* __restrict__ out, const float* __restrict__ rowMS)
{
    int col = blockIdx.x * 256 + threadIdx.x;
    int row = blockIdx.y;
    if (col < VV) {
        float M = rowMS[row * 2], Sv = rowMS[row * 2 + 1];
        size_t idx = (size_t)row * VV + col;
        out[idx] = __expf(out[idx] - M) / Sv;
    }
}

// ---------------------------------------------------------------------------
extern "C" void kernel_launch(void* const* d_in, const int* in_sizes, int n_in,
                              void* d_out, int out_size, void* d_ws, size_t ws_size,
                              hipStream_t stream) {
    const int*   tokens = (const int*)  d_in[0];
    const float* emb    = (const float*)d_in[1];
    const float* W      = (const float*)d_in[2];
    const float* U      = (const float*)d_in[3];
    const float* bias   = (const float*)d_in[4];
    const float* Wd     = (const float*)d_in[5];
    const float* bd     = (const float*)d_in[6];
    float* out = (float*)d_out;

    const size_t XP_BYTES   = (size_t)SS * BB * H3 * 2;     // 100,663,296
    const size_t WSU_BYTES  = (size_t)NWG * UBYTES;         // 1,572,864
    const size_t WSW_BYTES  = (size_t)32 * H3 * 8 * 2;      // 786,432
    const size_t HPUB_BYTES = 2 * (size_t)HBYTES;           // 131,072
    const size_t HLAST_BYTES= (size_t)BB * HH * 4;          // 131,072
    const size_t MASK_BYTES = (size_t)SS * 8;               // 4,096
    const size_t PART_BYTES = (size_t)393 * 64 * 2 * 4;     // 201,216

    char* ws = (char*)d_ws;
    _Float16* xp    = (_Float16*)ws;
    _Float16* wsU   = (_Float16*)(ws + XP_BYTES);
    _Float16* wsW   = (_Float16*)(ws + XP_BYTES + WSU_BYTES);
    char*     hpub  =            ws + XP_BYTES + WSU_BYTES + WSW_BYTES;
    float*    hlast = (float*)  (hpub + HPUB_BYTES);
    unsigned long long* maskb = (unsigned long long*)(hpub + HPUB_BYTES + HLAST_BYTES);
    float* partials = (float*)(hpub + HPUB_BYTES + HLAST_BYTES + MASK_BYTES);
    float* rowMS    = (float*)(hpub + HPUB_BYTES + HLAST_BYTES + MASK_BYTES + PART_BYTES);

    hipFuncSetAttribute((const void*)k2_scan,
                        hipFuncAttributeMaxDynamicSharedMemorySize, UBYTES);

    // tag-safe init: buf0 first expects tag1 -> init bit14=0 (0x00);
    //                buf1 first expects tag0 -> init bit14=1 (0x40)
    hipMemsetAsync(hpub, 0x00, HBYTES, stream);
    hipMemsetAsync(hpub + HBYTES, 0x40, HBYTES, stream);

    kPackW<<<32 * H3 / 256, 256, 0, stream>>>(W, wsW);
    kPackU<<<NWG, 256, 0, stream>>>(U, wsU);
    kMask<<<2, 256, 0, stream>>>(tokens, maskb);
    k1_embed_proj<<<dim3(12, 512), 256, 0, stream>>>(tokens, emb, wsW, bias, xp);

    k2_scan<<<NWG, 256, UBYTES, stream>>>(xp, wsU, bias, maskb, hpub, hlast);

    k3_logits<<<393, 256, 0, stream>>>(hlast, Wd, bd, out, partials);
    k3_reduce<<<64, 64, 0, stream>>>(partials, rowMS);
    k3_softmax<<<dim3((VV + 255) / 256, BB), 256, 0, stream>>>(out, rowMS);
}